// Round 11
// baseline (287.082 us; speedup 1.0000x reference)
//
#include <hip/hip_runtime.h>
#include <math.h>

// Problem constants (fixed by reference)
#define B_TOT   256
#define N_TOT   2304
#define IN_DIM  8
#define NC      10      // NUM_CLASSES
#define OD      16      // OUT_DIM
#define CD      160     // NC*OD
#define RBIAS   0.1f

#define NSL     256                     // n-slabs = routing grid (1 block/CU)
#define NPB     (N_TOT / NSL)           // 9 n per block
#define NTH     1024                    // 16 waves; block covers ALL 256 b
#define XRS     76                      // sh_x row stride (dwords, 16B-mult)
#define WPR     196                     // sh_wp i-row stride (dwords, 16B-mult)
#define WROW    (IN_DIM * CD)           // 1280 floats per W row
#define SRAW    (B_TOT * CD)            // 40960 floats per accumulator
#define NXCD    8

typedef __attribute__((ext_vector_type(8))) short bf16x8;
typedef __attribute__((ext_vector_type(4))) float f32x4;

// RNE round fp32 -> bf16 (top-aligned); exact-ish 2-way split (R9-verified)
__device__ __forceinline__ unsigned int rne_hi(unsigned int b) {
    return (b + 0x7FFFu + ((b >> 16) & 1u)) & 0xFFFF0000u;
}
__device__ __forceinline__ void split2(float f, unsigned int& h, unsigned int& l) {
    unsigned int xb = __float_as_uint(f);
    h = rne_hi(xb);
    float fl = f - __uint_as_float(h);
    l = __float_as_uint(fl) & 0xFFFF0000u;
}

// ===== Routing round, R11: MFMA v2.
// R1-R10 ledger: any W transport through scalar-K$ / LDS-broadcast /
// readlane is wall'd at >=49us/round (80 unique K$ lines/CU-nn x ~82cy
// serial service). MFMA's operand crossbar does the broadcast free, and
// R9 HW-verified the 16x16x32 frag maps (passed, absmax 0.0039). v2 fixes
// R9's delivery: (1) A<->B swapped so C=[d rows][b cols] -> softmax needs
// only 2 shfl/class; (2) W split/packed ONCE per block-nn into LDS
// [i][d][12] (uint4 frag reads), double-buffered; (3) 16-wave blocks,
// grid=256=1/CU, launch_bounds(1024,4) -> 4 waves/SIMD guaranteed.
// K=32 slots = 8i x 4 split-products (xh,xh,xl,xl)*(wh,wl,wh,wl).
template <int FIRST>
__global__ __launch_bounds__(NTH, 4) void routing_round(
    const float* __restrict__ x,      // [B, N, 8]
    const float* __restrict__ W,      // [N, 8, 160]
    const float* __restrict__ S_acc,  // [B, 160]
    float* __restrict__ rawT)         // [160][256] atomic accumulator
{
    __shared__ __align__(16) float        sh_x[B_TOT * XRS];    // 77.8 KB
    __shared__ __align__(16) unsigned int sh_wp[2][8 * WPR];    // 12.5 KB

    const int tid  = threadIdx.x;
    const int lane = tid & 63;
    const int w    = tid >> 6;          // 0..15: wave = b-group
    const int l    = lane & 15;         // A row (=d) / B col (=b) selector
    const int g    = lane >> 4;         // k-group -> i = g, g+4; C row grp

    const int bid   = blockIdx.x;                  // 0..255
    const int xcd   = bid & (NXCD - 1);            // XCD round-robin (R1)
    const int ySlab = xcd * 32 + (bid >> 3);       // 0..255
    const int n0    = ySlab * NPB;

    const int bglob = w * 16 + l;       // this lane's b (C column)

    // ---- stage x tile: [256 b][72 floats] -> sh_x[b][76], coalesced float4
    for (int k = tid; k < B_TOT * 18; k += NTH) {
        int bb = k / 18, off4 = k - bb * 18;
        float4 v = *(const float4*)(x + ((size_t)bb * N_TOT + n0) * IN_DIM + off4 * 4);
        *(float4*)(&sh_x[bb * XRS + off4 * 4]) = v;
    }
    // ---- stage W row n0: split+pack to sh_wp[0][i*WPR + d*12 + c]
    {
        const float* Wr = W + (size_t)n0 * WROW;
        for (int e = tid; e < WROW; e += NTH) {
            int i = e / 160, r = e - i * 160;
            int c = r >> 4, d = r & 15;
            unsigned int h, lo; split2(Wr[e], h, lo);
            sh_wp[0][i * WPR + d * 12 + c] = (h >> 16) | lo;   // (wh, wl)
        }
    }

    // ---- S fragments in C layout: S[c][reg] at (d = 4g+reg, b = bglob)
    float S[NC][4];
    if (!FIRST) {
        #pragma unroll
        for (int c = 0; c < NC; c++)
            #pragma unroll
            for (int rg = 0; rg < 4; rg++)
                S[c][rg] = S_acc[(size_t)bglob * CD + c * OD + 4 * g + rg];
    }

    f32x4 acc[NC];
    #pragma unroll
    for (int c = 0; c < NC; c++) acc[c] = (f32x4){0.f, 0.f, 0.f, 0.f};

    __syncthreads();   // x + wp[0] ready

    for (int nn = 0; nn < NPB; nn++) {
        const int cur = nn & 1;

        // stage next W row into alt buffer (overlaps with compute)
        if (nn + 1 < NPB) {
            const float* Wr = W + (size_t)(n0 + nn + 1) * WROW;
            for (int e = tid; e < WROW; e += NTH) {
                int i = e / 160, r = e - i * 160;
                int c = r >> 4, d = r & 15;
                unsigned int h, lo; split2(Wr[e], h, lo);
                sh_wp[cur ^ 1][i * WPR + d * 12 + c] = (h >> 16) | lo;
            }
        }

        // ---- B frag (x side, R9's verified packing): lane b = bglob
        union { unsigned int d[4]; bf16x8 v; } Bx;
        {
            float x0 = sh_x[bglob * XRS + nn * IN_DIM + g];
            float x1 = sh_x[bglob * XRS + nn * IN_DIM + g + 4];
            unsigned int h0, l0, h1, l1;
            split2(x0, h0, l0); split2(x1, h1, l1);
            Bx.d[0] = (h0 >> 16) | h0;   // k 4g..:   xh,xh
            Bx.d[1] = (l0 >> 16) | l0;   //           xl,xl
            Bx.d[2] = (h1 >> 16) | h1;   // k 16+4g.. xh',xh'
            Bx.d[3] = (l1 >> 16) | l1;   //           xl',xl'
        }

        // ---- A frag dwords for all 10 classes (i=g and i=g+4 halves)
        const unsigned int* wp0 = &sh_wp[cur][g       * WPR + l * 12];
        const unsigned int* wp1 = &sh_wp[cur][(g + 4) * WPR + l * 12];
        uint4 a0 = *(const uint4*)(wp0);      // c0..3,  i=g
        uint4 a1 = *(const uint4*)(wp0 + 4);  // c4..7
        uint2 a2 = *(const uint2*)(wp0 + 8);  // c8,9
        uint4 b0 = *(const uint4*)(wp1);      // c0..3,  i=g+4
        uint4 b1 = *(const uint4*)(wp1 + 4);
        uint2 b2 = *(const uint2*)(wp1 + 8);

#define MK_A(pa, pb) Af.d[0] = (pa); Af.d[1] = (pa); Af.d[2] = (pb); Af.d[3] = (pb)

        if (!FIRST) {
            union { unsigned int d[4]; bf16x8 v; } Af;
            float lg[NC];
            // pass 1: u -> logit partial (4-FMA dot with S)
#define LG1(idx, pa, pb) { MK_A(pa, pb);                                     \
            f32x4 u = __builtin_amdgcn_mfma_f32_16x16x32_bf16(               \
                          Af.v, Bx.v, (f32x4){0.f,0.f,0.f,0.f}, 0, 0, 0);    \
            lg[idx] = u[0]*S[idx][0] + u[1]*S[idx][1]                        \
                    + u[2]*S[idx][2] + u[3]*S[idx][3]; }
            LG1(0, a0.x, b0.x) LG1(1, a0.y, b0.y) LG1(2, a0.z, b0.z)
            LG1(3, a0.w, b0.w) LG1(4, a1.x, b1.x) LG1(5, a1.y, b1.y)
            LG1(6, a1.z, b1.z) LG1(7, a1.w, b1.w) LG1(8, a2.x, b2.x)
            LG1(9, a2.y, b2.y)
#undef LG1
            // reduce over the 4 g-groups (rows 4g+reg cover d=0..15)
            #pragma unroll
            for (int c = 0; c < NC; c++) {
                float t = lg[c];
                t += __shfl_xor(t, 16, 64);
                t += __shfl_xor(t, 32, 64);
                lg[c] = t;
            }
            float m = lg[0];
            #pragma unroll
            for (int c = 1; c < NC; c++) m = fmaxf(m, lg[c]);
            float den = 0.f;
            #pragma unroll
            for (int c = 0; c < NC; c++) { lg[c] = __expf(lg[c] - m); den += lg[c]; }
            const float rden = 1.f / den;
            // pass 2: recompute u (frag dwords still in regs), acc += cw*u
#define AC2(idx, pa, pb) { MK_A(pa, pb);                                     \
            f32x4 u = __builtin_amdgcn_mfma_f32_16x16x32_bf16(               \
                          Af.v, Bx.v, (f32x4){0.f,0.f,0.f,0.f}, 0, 0, 0);    \
            float cwv = lg[idx] * rden;                                      \
            acc[idx][0] = fmaf(cwv, u[0], acc[idx][0]);                      \
            acc[idx][1] = fmaf(cwv, u[1], acc[idx][1]);                      \
            acc[idx][2] = fmaf(cwv, u[2], acc[idx][2]);                      \
            acc[idx][3] = fmaf(cwv, u[3], acc[idx][3]); }
            AC2(0, a0.x, b0.x) AC2(1, a0.y, b0.y) AC2(2, a0.z, b0.z)
            AC2(3, a0.w, b0.w) AC2(4, a1.x, b1.x) AC2(5, a1.y, b1.y)
            AC2(6, a1.z, b1.z) AC2(7, a1.w, b1.w) AC2(8, a2.x, b2.x)
            AC2(9, a2.y, b2.y)
#undef AC2
        } else {
            // round 0: uniform cw folded into finalize -> acc = mfma(A,B,acc)
            union { unsigned int d[4]; bf16x8 v; } Af;
#define AC0(idx, pa, pb) { MK_A(pa, pb);                                     \
            acc[idx] = __builtin_amdgcn_mfma_f32_16x16x32_bf16(              \
                           Af.v, Bx.v, acc[idx], 0, 0, 0); }
            AC0(0, a0.x, b0.x) AC0(1, a0.y, b0.y) AC0(2, a0.z, b0.z)
            AC0(3, a0.w, b0.w) AC0(4, a1.x, b1.x) AC0(5, a1.y, b1.y)
            AC0(6, a1.z, b1.z) AC0(7, a1.w, b1.w) AC0(8, a2.x, b2.x)
            AC0(9, a2.y, b2.y)
#undef AC0
        }
#undef MK_A

        __syncthreads();   // publish next W buffer; cur fully consumed
    }

    // ---- commit: atomicAdd into rawT[cd][b]; quarter-wave-coalesced
    #pragma unroll
    for (int c = 0; c < NC; c++)
        #pragma unroll
        for (int rg = 0; rg < 4; rg++)
            atomicAdd(rawT + (size_t)(c * OD + 4 * g + rg) * B_TOT + bglob,
                      acc[c][rg]);
}

// ===== Zero the three raw accumulators (re-poison safe: first touch each
// call). 3*40960 floats = 30720 float4 -> 120 blocks x 256 threads exact.
__global__ __launch_bounds__(256) void zero_raws(float4* __restrict__ p)
{
    p[(size_t)blockIdx.x * 256 + threadIdx.x] = (float4){0.f, 0.f, 0.f, 0.f};
}

// ===== Finalize (R10 verbatim): 40 blocks x 256 threads; thread p owns
// float4 #p of the [B][160] view; reads rawT[cd][b] then:
//   mode 0: S_acc = raw*0.1 + 0.1     mode 1: S_acc += raw + 0.1
//   mode 2: s = raw + 0.1; squash -> v_out (2 shfl_xor over the 4 dq lanes)
__global__ __launch_bounds__(256) void finalize_round(
    const float* __restrict__ rawT,   // [160][256]
    float* __restrict__ S_acc,        // [256][160]
    float* __restrict__ v_out,        // [256][10][16]
    int mode)
{
    const int p   = blockIdx.x * 256 + threadIdx.x;   // 0..10239
    const int b   = p / 40;
    const int rem = p - b * 40;                       // c*4 + dq
    const int cd0 = rem * 4;                          // = c*16 + dq*4

    float t0 = rawT[(size_t)(cd0 + 0) * B_TOT + b];
    float t1 = rawT[(size_t)(cd0 + 1) * B_TOT + b];
    float t2 = rawT[(size_t)(cd0 + 2) * B_TOT + b];
    float t3 = rawT[(size_t)(cd0 + 3) * B_TOT + b];

    if (mode == 0) {
        float4 o = { t0 * 0.1f + RBIAS, t1 * 0.1f + RBIAS,
                     t2 * 0.1f + RBIAS, t3 * 0.1f + RBIAS };
        ((float4*)S_acc)[p] = o;
    } else if (mode == 1) {
        float4 o = ((const float4*)S_acc)[p];
        o.x += t0 + RBIAS; o.y += t1 + RBIAS;
        o.z += t2 + RBIAS; o.w += t3 + RBIAS;
        ((float4*)S_acc)[p] = o;
    } else {
        const float s0 = t0 + RBIAS, s1 = t1 + RBIAS;
        const float s2 = t2 + RBIAS, s3 = t3 + RBIAS;
        float ss = s0 * s0 + s1 * s1 + s2 * s2 + s3 * s3;
        ss += __shfl_xor(ss, 1, 64);
        ss += __shfl_xor(ss, 2, 64);
        const float norm = sqrtf(ss);
        const float k2 = norm / (1.0f + ss);
        float4 v = { s0 * k2, s1 * k2, s2 * k2, s3 * k2 };
        ((float4*)v_out)[p] = v;
    }
}

extern "C" void kernel_launch(void* const* d_in, const int* in_sizes, int n_in,
                              void* d_out, int out_size, void* d_ws, size_t ws_size,
                              hipStream_t stream) {
    const float* x = (const float*)d_in[0];   // [256,2304,8]
    const float* W = (const float*)d_in[1];   // [2304,8,160]
    float* out = (float*)d_out;               // [256,10,16]

    // Workspace: 3 raw accumulators + S_acc = 655 KB.
    // Every byte read is written first each call (zero_raws; S_acc via mode0).
    float* raw0  = (float*)d_ws;
    float* raw1  = raw0 + SRAW;
    float* raw2  = raw1 + SRAW;
    float* S_acc = raw2 + SRAW;

    const dim3 rgrid(NSL);    // 256 blocks = 1/CU, 16 waves each

    zero_raws<<<120, 256, 0, stream>>>((float4*)raw0);   // all 3 raws

    // Round 0 (uniform cw; 0.1 folded into finalize scale)
    routing_round<1><<<rgrid, NTH, 0, stream>>>(x, W, S_acc, raw0);
    finalize_round<<<40, 256, 0, stream>>>(raw0, S_acc, out, 0);

    // Round 1
    routing_round<0><<<rgrid, NTH, 0, stream>>>(x, W, S_acc, raw1);
    finalize_round<<<40, 256, 0, stream>>>(raw1, S_acc, out, 1);

    // Round 2 (+final squash)
    routing_round<0><<<rgrid, NTH, 0, stream>>>(x, W, S_acc, raw2);
    finalize_round<<<40, 256, 0, stream>>>(raw2, S_acc, out, 2);
}